// Round 14
// baseline (316.997 us; speedup 1.0000x reference)
//
#include <hip/hip_runtime.h>

// KNN argmin over L2, round 14: wave-desynchronized phase A + finer rescore
// granularity when workspace allows.
//
// R13 post-mortem: LDS-shared staging regressed (barrier coupling, 42%
// MfmaUtil); and recomputed L2 demand (22 B/cyc/CU) shows L2 supply was
// NEVER the R12 limiter. The persistent MfmaUtil+VALUBusy ~= 100% across
// R8/R12/R13 indicates phase-locked waves: co-resident waves execute the
// same step chain (VALU init -> MFMA x6 -> VALU fold) in lockstep, so the
// MFMA pipe idles during the common VALU phase. Fix: rotate each wave's
// step order within every 256-support block by 4*w (min is commutative),
// desynchronizing the pipes. phaseA otherwise reverts to the proven R12
// skeleton (pinned Q-frags in AGPRs, C init -0.5*sq, a/b prefetch).
//
// SBLK templating: path A (ws >= 20.07 MB): SBLK=128 (halves phaseB rescore
// traffic), dedicated S_T written by fused prep, 3 launches. path B
// (proven 12.07 MB): SBLK=256, S_T aliases panels, post-phaseA transpose.
//
// Filter certification unchanged: 3-term split (sh.qh + sl.qh + sh.ql),
// key error <= ~0.014 << EPS=0.05 => rescore set provably contains the
// true first-argmin support. Phase B compares exact fp32 keys with
// strict-< ascending scan + lexicographic cross-lane reduce => np.argmin
// first-index semantics.

#define NTOT   16384
#define DIM    64
#define EPS    0.05f
#define FLT_BIG 3.4e38f

typedef __attribute__((ext_vector_type(8))) short short8;
typedef __attribute__((ext_vector_type(4))) float float4v;

__device__ __forceinline__ ushort bf16_rne(float x) {
  unsigned u = __float_as_uint(x);
  return (ushort)((u + 0x7FFF + ((u >> 16) & 1)) >> 16);
}

// Opaque def: forbids rematerialization (forces register residency).
__device__ __forceinline__ void pin8(short8& v) {
  asm volatile("" : "+v"(v));
}

// ---------------------------------------------------------------------------
// Fused prep: blocks 0..255 -> S (panels + sqS, optionally S_T);
// blocks 256..511 -> Q (panels only). Panel layout (R8-proven):
//   off(r,k) = (r>>4)*1024 + (k>>5)*512 + (((k&31)>>3)*16 + (r&15))*8 + (k&7)
__global__ __launch_bounds__(256) void k_prep(
    const float* __restrict__ S, const float* __restrict__ Q,
    ushort* __restrict__ Sh, ushort* __restrict__ Sl,
    ushort* __restrict__ Qh, ushort* __restrict__ Ql,
    float* __restrict__ sqS, float* __restrict__ S_T) {
  __shared__ float tile[64][65];
  const int tid = threadIdx.x;
  const bool isS = blockIdx.x < 256;
  const int rbase = (blockIdx.x & 255) * 64;
  const float* __restrict__ src = isS ? S : Q;
  ushort* __restrict__ dh = isS ? Sh : Qh;
  ushort* __restrict__ dl = isS ? Sl : Ql;

  const int tx = tid & 63;
  const int ty = tid >> 6;
#pragma unroll
  for (int i = 0; i < 16; ++i) {
    const int r = i * 4 + ty;
    tile[r][tx] = src[(size_t)(rbase + r) * DIM + tx];  // coalesced
  }
  __syncthreads();

  if (isS && S_T != nullptr) {  // transposed copy (coalesced, pad-safe)
#pragma unroll
    for (int i = 0; i < 16; ++i) {
      const int d = i * 4 + ty;
      S_T[(size_t)d * NTOT + rbase + tx] = tile[tx][d];
    }
  }

  const int panel = tid >> 6;           // 0..3
  const int half = (tid >> 5) & 1;      // k-half
  const int slot0 = (tid & 31) * 2;     // slot = q8*16 + m
#pragma unroll
  for (int ss = 0; ss < 2; ++ss) {
    const int s = slot0 + ss;
    const int m = s & 15;
    const int q8 = s >> 4;
    const int row = panel * 16 + m;
    const int kb = half * 32 + q8 * 8;
    short8 hv, lv;
#pragma unroll
    for (int j = 0; j < 8; ++j) {
      const float x = tile[row][kb + j];
      const ushort h = bf16_rne(x);
      const float hf = __uint_as_float(((unsigned)h) << 16);
      hv[j] = (short)h;
      lv[j] = (short)bf16_rne(x - hf);
    }
    const size_t goff =
        (size_t)((rbase >> 4) + panel) * 1024 + (size_t)half * 512 + (size_t)s * 8;
    *(short8*)&dh[goff] = hv;
    *(short8*)&dl[goff] = lv;
  }

  if (isS && tid < 64) {
    float acc = 0.0f;
#pragma unroll
    for (int d = 0; d < DIM; ++d) {
      const float v = tile[tid][d];
      acc = fmaf(v, v, acc);
    }
    sqS[rbase + tid] = acc;
  }
}

// ---------------------------------------------------------------------------
// Standalone transpose (path B only; runs AFTER phaseA when S_T aliases).
__global__ __launch_bounds__(256) void k_transpose(
    const float* __restrict__ in, float* __restrict__ outT) {
  __shared__ float tile[64][65];
  const int tx = threadIdx.x & 63;
  const int ty = threadIdx.x >> 6;
  const int rbase = blockIdx.x * 64;
#pragma unroll
  for (int i = 0; i < 16; ++i) {
    const int r = i * 4 + ty;
    tile[r][tx] = in[(size_t)(rbase + r) * DIM + tx];
  }
  __syncthreads();
#pragma unroll
  for (int i = 0; i < 16; ++i) {
    const int d = i * 4 + ty;
    outT[(size_t)d * NTOT + rbase + tx] = tile[tx][d];
  }
}

// ---------------------------------------------------------------------------
// Phase A: block = 4 waves; wave w: 64 queries x 512 supports.
// grid = (8 splits, 256 q-tiles). 16x16x32 bf16 MFMA; layouts HW-verified
// R4-R13. Wave-desynchronized step order within each SBLK-support block.

#define MFMA16(A, B, C) __builtin_amdgcn_mfma_f32_16x16x32_bf16(A, B, C, 0, 0, 0)

#define STEP_COMPUTE(H0, H1, L0, L1, SQ)                                   \
  do {                                                                     \
    _Pragma("unroll")                                                      \
    for (int t = 0; t < 4; ++t) {                                          \
      float4v a;                                                           \
      a[0] = -0.5f * SQ.x;                                                 \
      a[1] = -0.5f * SQ.y;                                                 \
      a[2] = -0.5f * SQ.z;                                                 \
      a[3] = -0.5f * SQ.w;                                                 \
      a = MFMA16(H0, qh[t][0], a);                                         \
      a = MFMA16(H1, qh[t][1], a);                                         \
      a = MFMA16(L0, qh[t][0], a);                                         \
      a = MFMA16(L1, qh[t][1], a);                                         \
      a = MFMA16(H0, qlo[t][0], a);                                        \
      a = MFMA16(H1, qlo[t][1], a);                                        \
      bmr[t] = fmaxf(bmr[t], fmaxf(fmaxf(a[0], a[1]), fmaxf(a[2], a[3]))); \
    }                                                                      \
  } while (0)

#define LOAD_FRAGS(H0, H1, L0, L1, SQ, ST)                                 \
  do {                                                                     \
    const int off_ = (ST) * 1024;                                          \
    H0 = *(const short8*)(pSh + off_);                                     \
    H1 = *(const short8*)(pSh + off_ + 512);                               \
    L0 = *(const short8*)(pSl + off_);                                     \
    L1 = *(const short8*)(pSl + off_ + 512);                               \
    SQ = *(const float4*)(psq + (ST) * 16);                                \
  } while (0)

template <int SBLK>
__global__ __launch_bounds__(256, 3) void k_phaseA(
    const ushort* __restrict__ Sh, const ushort* __restrict__ Sl,
    const ushort* __restrict__ Qh, const ushort* __restrict__ Ql,
    const float* __restrict__ sqS, float* __restrict__ bmin) {
  constexpr int NSB = NTOT / SBLK;        // total bmin blocks
  constexpr int SPBS = SBLK / 16;         // steps per block (8 or 16)
  constexpr int NBW = 512 / SBLK;         // blocks per wave (4 or 2)
  constexpr int PH = SPBS / 4;            // per-wave phase stride

  const int tid = threadIdx.x;
  const int l = tid & 63;
  const int w = tid >> 6;
  const int lm = l & 15;
  const int lq = l >> 4;
  const int split = blockIdx.x;       // 0..7
  const int qbase = blockIdx.y * 64;
  const int sbase = split * 2048 + w * 512;
  const int off = w * PH;             // desync rotation (wave-uniform)

  // Query (B) fragments, hi and lo: pinned (resident in AGPRs, R12-proven).
  short8 qh[4][2], qlo[4][2];
#pragma unroll
  for (int t = 0; t < 4; ++t) {
    const size_t pb = (size_t)((qbase >> 4) + t) * 1024 + (size_t)l * 8;
    qh[t][0] = *(const short8*)&Qh[pb];
    qh[t][1] = *(const short8*)&Qh[pb + 512];
    qlo[t][0] = *(const short8*)&Ql[pb];
    qlo[t][1] = *(const short8*)&Ql[pb + 512];
  }
#pragma unroll
  for (int t = 0; t < 4; ++t) {
    pin8(qh[t][0]);
    pin8(qh[t][1]);
    pin8(qlo[t][0]);
    pin8(qlo[t][1]);
  }

  const ushort* pSh = Sh + (size_t)(sbase >> 4) * 1024 + (size_t)l * 8;
  const ushort* pSl = Sl + (size_t)(sbase >> 4) * 1024 + (size_t)l * 8;
  const float* psq = sqS + sbase + lq * 4;

  // Permuted step sequence: n-th visited step.
  auto step_of = [&](int n) -> int {
    const int blk = n / SPBS;
    const int i = n & (SPBS - 1);
    return blk * SPBS + ((i + off) & (SPBS - 1));
  };

  // Copy-free double buffer over the permuted sequence.
  short8 h0a, h1a, l0a, l1a, h0b, h1b, l0b, l1b;
  float4 sqa, sqb;
  LOAD_FRAGS(h0a, h1a, l0a, l1a, sqa, step_of(0));
  LOAD_FRAGS(h0b, h1b, l0b, l1b, sqb, step_of(1));

  float bmr[4] = {-FLT_BIG, -FLT_BIG, -FLT_BIG, -FLT_BIG};

#pragma unroll
  for (int n = 0; n < 32; n += 2) {
    STEP_COMPUTE(h0a, h1a, l0a, l1a, sqa);
    if (n + 2 < 32) LOAD_FRAGS(h0a, h1a, l0a, l1a, sqa, step_of(n + 2));
    STEP_COMPUTE(h0b, h1b, l0b, l1b, sqb);
    if (n + 3 < 32) LOAD_FRAGS(h0b, h1b, l0b, l1b, sqb, step_of(n + 3));
    if (((n + 2) & (SPBS - 1)) == 0) {  // finished block (n+1 was its last)
      const int blk = n / SPBS;         // 0..NBW-1
      const int gb = split * (2048 / SBLK) + w * NBW + blk;
#pragma unroll
      for (int t = 0; t < 4; ++t) {
        float v = bmr[t];
        v = fmaxf(v, __shfl_xor(v, 16, 64));
        v = fmaxf(v, __shfl_xor(v, 32, 64));
        if (lq == 0) bmin[(size_t)(qbase + t * 16 + lm) * NSB + gb] = -2.0f * v;
        bmr[t] = -FLT_BIG;
      }
    }
  }
}

// ---------------------------------------------------------------------------
// Phase B: one wave per query; coalesced rescore from S_T.
template <int SBLK>
__global__ __launch_bounds__(256) void k_phaseB(
    const float* __restrict__ S_T,   // [64][NTOT]
    const float* __restrict__ Q,     // [NTOT][64]
    const float* __restrict__ sqS, const float* __restrict__ bmin,
    const float* __restrict__ onehot, float* __restrict__ out) {
  constexpr int NSB = NTOT / SBLK;    // 64 or 128
  constexpr int NB64 = NSB / 64;      // 1 or 2
  constexpr int SPL = SBLK / 64;      // supports per lane: 4 or 2

  __shared__ float sQrow[4][64];
  const int lane = threadIdx.x & 63;
  const int w = threadIdx.x >> 6;
  const int q = blockIdx.x * 4 + w;

  if (lane < 16)
    *(float4*)&sQrow[w][lane * 4] = *(const float4*)&Q[(size_t)q * DIM + lane * 4];
  __syncthreads();

  float bv[NB64];
#pragma unroll
  for (int j = 0; j < NB64; ++j) bv[j] = bmin[(size_t)q * NSB + j * 64 + lane];
  float m = bv[0];
#pragma unroll
  for (int j = 1; j < NB64; ++j) m = fminf(m, bv[j]);
#pragma unroll
  for (int d = 1; d < 64; d <<= 1) m = fminf(m, __shfl_xor(m, d, 64));
  const float thr = m + EPS;

  float bk = FLT_BIG;
  int bi = 0;
#pragma unroll
  for (int j = 0; j < NB64; ++j) {
    unsigned long long msk = __ballot(bv[j] <= thr);
    while (msk) {  // ascending block order; wave-uniform control
      const int b = j * 64 + (__ffsll((long long)msk) - 1);
      msk &= msk - 1;
      const int s0 = b * SBLK + lane * SPL;
      if (SPL == 4) {
        float a0 = 0.f, a1 = 0.f, a2 = 0.f, a3 = 0.f;
#pragma unroll
        for (int c = 0; c < 16; ++c) {
          const float4 qv = *(const float4*)&sQrow[w][c * 4];
          const float4 s0v = *(const float4*)&S_T[(size_t)(c * 4 + 0) * NTOT + s0];
          const float4 s1v = *(const float4*)&S_T[(size_t)(c * 4 + 1) * NTOT + s0];
          const float4 s2v = *(const float4*)&S_T[(size_t)(c * 4 + 2) * NTOT + s0];
          const float4 s3v = *(const float4*)&S_T[(size_t)(c * 4 + 3) * NTOT + s0];
          a0 = fmaf(qv.x, s0v.x, a0); a1 = fmaf(qv.x, s0v.y, a1);
          a2 = fmaf(qv.x, s0v.z, a2); a3 = fmaf(qv.x, s0v.w, a3);
          a0 = fmaf(qv.y, s1v.x, a0); a1 = fmaf(qv.y, s1v.y, a1);
          a2 = fmaf(qv.y, s1v.z, a2); a3 = fmaf(qv.y, s1v.w, a3);
          a0 = fmaf(qv.z, s2v.x, a0); a1 = fmaf(qv.z, s2v.y, a1);
          a2 = fmaf(qv.z, s2v.z, a2); a3 = fmaf(qv.z, s2v.w, a3);
          a0 = fmaf(qv.w, s3v.x, a0); a1 = fmaf(qv.w, s3v.y, a1);
          a2 = fmaf(qv.w, s3v.z, a2); a3 = fmaf(qv.w, s3v.w, a3);
        }
        const float4 sq4 = *(const float4*)&sqS[s0];
        const float k0 = fmaf(-2.f, a0, sq4.x);
        const float k1 = fmaf(-2.f, a1, sq4.y);
        const float k2 = fmaf(-2.f, a2, sq4.z);
        const float k3 = fmaf(-2.f, a3, sq4.w);
        bool u;  // ascending index, strict <
        u = k0 < bk; bk = u ? k0 : bk; bi = u ? s0 : bi;
        u = k1 < bk; bk = u ? k1 : bk; bi = u ? (s0 + 1) : bi;
        u = k2 < bk; bk = u ? k2 : bk; bi = u ? (s0 + 2) : bi;
        u = k3 < bk; bk = u ? k3 : bk; bi = u ? (s0 + 3) : bi;
      } else {
        float a0 = 0.f, a1 = 0.f;
#pragma unroll
        for (int c = 0; c < 16; ++c) {
          const float4 qv = *(const float4*)&sQrow[w][c * 4];
          const float2 s0v = *(const float2*)&S_T[(size_t)(c * 4 + 0) * NTOT + s0];
          const float2 s1v = *(const float2*)&S_T[(size_t)(c * 4 + 1) * NTOT + s0];
          const float2 s2v = *(const float2*)&S_T[(size_t)(c * 4 + 2) * NTOT + s0];
          const float2 s3v = *(const float2*)&S_T[(size_t)(c * 4 + 3) * NTOT + s0];
          a0 = fmaf(qv.x, s0v.x, a0); a1 = fmaf(qv.x, s0v.y, a1);
          a0 = fmaf(qv.y, s1v.x, a0); a1 = fmaf(qv.y, s1v.y, a1);
          a0 = fmaf(qv.z, s2v.x, a0); a1 = fmaf(qv.z, s2v.y, a1);
          a0 = fmaf(qv.w, s3v.x, a0); a1 = fmaf(qv.w, s3v.y, a1);
        }
        const float2 sq2 = *(const float2*)&sqS[s0];
        const float k0 = fmaf(-2.f, a0, sq2.x);
        const float k1 = fmaf(-2.f, a1, sq2.y);
        bool u;
        u = k0 < bk; bk = u ? k0 : bk; bi = u ? s0 : bi;
        u = k1 < bk; bk = u ? k1 : bk; bi = u ? (s0 + 1) : bi;
      }
    }
  }
  // Cross-lane lexicographic argmin on exact keys => first-index semantics.
#pragma unroll
  for (int d = 1; d < 64; d <<= 1) {
    const float ok = __shfl_xor(bk, d, 64);
    const int oi = __shfl_xor(bi, d, 64);
    const bool u = (ok < bk) || (ok == bk && oi < bi);
    bk = u ? ok : bk;
    bi = u ? oi : bi;
  }
  // Label: one-hot rows exact {0,1}; first 1 == np.argmax.
  const float ov = onehot[(size_t)bi * 64 + lane];
  const unsigned long long lmask = __ballot(ov > 0.5f);
  const int label = __ffsll((long long)lmask) - 1;
  out[(size_t)q * 64 + lane] = (lane == label) ? 1.0f : 0.0f;
}

// ---------------------------------------------------------------------------
extern "C" void kernel_launch(void* const* d_in, const int* in_sizes, int n_in,
                              void* d_out, int out_size, void* d_ws, size_t ws_size,
                              hipStream_t stream) {
  const float* S = (const float*)d_in[0];   // [16384][64]
  const float* Q = (const float*)d_in[1];   // [16384][64]
  const float* OH = (const float*)d_in[2];  // [16384][64]
  float* out = (float*)d_out;

  char* ws = (char*)d_ws;
  ushort* Sh = (ushort*)ws;                                  // [0, 2MB)
  ushort* Sl = (ushort*)(ws + (2u << 20));                   // [2, 4MB)
  ushort* Qh = (ushort*)(ws + (4u << 20));                   // [4, 6MB)
  ushort* Ql = (ushort*)(ws + (6u << 20));                   // [6, 8MB)

  // Path A (ws >= 20.07 MB): SBLK=128, dedicated S_T, fused prep, 3 launches.
  // Path B (proven 12.07 MB): SBLK=256, S_T aliases panels, 4 launches.
  const bool pathA = ws_size >= ((20u << 20) + (64u << 10));
  if (pathA) {
    float* S_T = (float*)(ws + (8u << 20));                  // [8, 12MB)
    float* sqS = (float*)(ws + (12u << 20));                 // 64 KB
    float* bmin = (float*)(ws + (12u << 20) + (64u << 10));  // 8 MB
    k_prep<<<dim3(512), 256, 0, stream>>>(S, Q, Sh, Sl, Qh, Ql, sqS, S_T);
    k_phaseA<128><<<dim3(8, NTOT / 64), 256, 0, stream>>>(Sh, Sl, Qh, Ql, sqS, bmin);
    k_phaseB<128><<<dim3(NTOT / 4), 256, 0, stream>>>(S_T, Q, sqS, bmin, OH, out);
  } else {
    float* S_T = (float*)ws;                                 // aliases Sh+Sl
    float* sqS = (float*)(ws + (8u << 20));                  // 64 KB
    float* bmin = (float*)(ws + (8u << 20) + (64u << 10));   // 4 MB
    k_prep<<<dim3(512), 256, 0, stream>>>(S, Q, Sh, Sl, Qh, Ql, sqS, nullptr);
    k_phaseA<256><<<dim3(8, NTOT / 64), 256, 0, stream>>>(Sh, Sl, Qh, Ql, sqS, bmin);
    k_transpose<<<dim3(NTOT / 64), 256, 0, stream>>>(S, S_T);
    k_phaseB<256><<<dim3(NTOT / 4), 256, 0, stream>>>(S_T, Q, sqS, bmin, OH, out);
  }
  (void)in_sizes; (void)n_in; (void)out_size; (void)ws_size;
}

// Round 15
// 186.124 us; speedup vs baseline: 1.7031x; 1.7031x over previous
//
#include <hip/hip_runtime.h>

// KNN argmin over L2, round 15: R12-exact phase A + 128-granular bmin.
//
// R14 post-mortem: the permuted/templated phaseA rewrite spilled to scratch
// (FETCH 263MB + WRITE 458MB of HBM = spill traffic, 218us). Reverted to
// the R12-proven phaseA text verbatim; the ONLY diff is the epilogue
// condition: block-min fold/write every 8 steps (128 supports) instead of
// 16, via a template constant. This halves phaseB rescore traffic
// (candidate block 64KB -> 32KB; candidate count C~1 unchanged since EPS
// and key density are unchanged).
// R14 also proved ws_size >= 20.07 MB (pathA executed) -> SBLK=128 layout
// fits; pathB (SBLK=256, 12.07MB, R12-proven) kept as fallback.
//
// Filter certification unchanged: 3-term split (sh.qh + sl.qh + sh.ql),
// key error <= ~0.014 << EPS=0.05 => rescore set provably contains the
// true first-argmin support. Phase B compares exact fp32 keys with
// strict-< ascending scan + lexicographic cross-lane reduce => np.argmin
// first-index semantics.

#define NTOT   16384
#define DIM    64
#define EPS    0.05f
#define FLT_BIG 3.4e38f

typedef __attribute__((ext_vector_type(8))) short short8;
typedef __attribute__((ext_vector_type(4))) float float4v;

__device__ __forceinline__ ushort bf16_rne(float x) {
  unsigned u = __float_as_uint(x);
  return (ushort)((u + 0x7FFF + ((u >> 16) & 1)) >> 16);
}

// Opaque def: forbids rematerialization (forces register residency).
__device__ __forceinline__ void pin8(short8& v) {
  asm volatile("" : "+v"(v));
}

// ---------------------------------------------------------------------------
// Fused prep: blocks 0..255 -> S (panels + sqS, optionally S_T);
// blocks 256..511 -> Q (panels only). Panel layout (R8-proven):
//   off(r,k) = (r>>4)*1024 + (k>>5)*512 + (((k&31)>>3)*16 + (r&15))*8 + (k&7)
__global__ __launch_bounds__(256) void k_prep(
    const float* __restrict__ S, const float* __restrict__ Q,
    ushort* __restrict__ Sh, ushort* __restrict__ Sl,
    ushort* __restrict__ Qh, ushort* __restrict__ Ql,
    float* __restrict__ sqS, float* __restrict__ S_T) {
  __shared__ float tile[64][65];
  const int tid = threadIdx.x;
  const bool isS = blockIdx.x < 256;
  const int rbase = (blockIdx.x & 255) * 64;
  const float* __restrict__ src = isS ? S : Q;
  ushort* __restrict__ dh = isS ? Sh : Qh;
  ushort* __restrict__ dl = isS ? Sl : Ql;

  const int tx = tid & 63;
  const int ty = tid >> 6;
#pragma unroll
  for (int i = 0; i < 16; ++i) {
    const int r = i * 4 + ty;
    tile[r][tx] = src[(size_t)(rbase + r) * DIM + tx];  // coalesced
  }
  __syncthreads();

  if (isS && S_T != nullptr) {  // transposed copy (coalesced, pad-safe)
#pragma unroll
    for (int i = 0; i < 16; ++i) {
      const int d = i * 4 + ty;
      S_T[(size_t)d * NTOT + rbase + tx] = tile[tx][d];
    }
  }

  const int panel = tid >> 6;           // 0..3
  const int half = (tid >> 5) & 1;      // k-half
  const int slot0 = (tid & 31) * 2;     // slot = q8*16 + m
#pragma unroll
  for (int ss = 0; ss < 2; ++ss) {
    const int s = slot0 + ss;
    const int m = s & 15;
    const int q8 = s >> 4;
    const int row = panel * 16 + m;
    const int kb = half * 32 + q8 * 8;
    short8 hv, lv;
#pragma unroll
    for (int j = 0; j < 8; ++j) {
      const float x = tile[row][kb + j];
      const ushort h = bf16_rne(x);
      const float hf = __uint_as_float(((unsigned)h) << 16);
      hv[j] = (short)h;
      lv[j] = (short)bf16_rne(x - hf);
    }
    const size_t goff =
        (size_t)((rbase >> 4) + panel) * 1024 + (size_t)half * 512 + (size_t)s * 8;
    *(short8*)&dh[goff] = hv;
    *(short8*)&dl[goff] = lv;
  }

  if (isS && tid < 64) {
    float acc = 0.0f;
#pragma unroll
    for (int d = 0; d < DIM; ++d) {
      const float v = tile[tid][d];
      acc = fmaf(v, v, acc);
    }
    sqS[rbase + tid] = acc;
  }
}

// ---------------------------------------------------------------------------
// Standalone transpose (path B only; runs AFTER phaseA when S_T aliases).
__global__ __launch_bounds__(256) void k_transpose(
    const float* __restrict__ in, float* __restrict__ outT) {
  __shared__ float tile[64][65];
  const int tx = threadIdx.x & 63;
  const int ty = threadIdx.x >> 6;
  const int rbase = blockIdx.x * 64;
#pragma unroll
  for (int i = 0; i < 16; ++i) {
    const int r = i * 4 + ty;
    tile[r][tx] = in[(size_t)(rbase + r) * DIM + tx];
  }
  __syncthreads();
#pragma unroll
  for (int i = 0; i < 16; ++i) {
    const int d = i * 4 + ty;
    outT[(size_t)d * NTOT + rbase + tx] = tile[tx][d];
  }
}

// ---------------------------------------------------------------------------
// Phase A: block = 4 waves; wave w: 64 queries x 512 supports.
// grid = (8 splits, 256 q-tiles). 16x16x32 bf16 MFMA; layouts HW-verified
// R4-R13. Text identical to R12 except the templated epilogue period BST
// (steps per bmin block: 8 -> 128-support granularity, 16 -> 256).

#define MFMA16(A, B, C) __builtin_amdgcn_mfma_f32_16x16x32_bf16(A, B, C, 0, 0, 0)

#define STEP_COMPUTE(H0, H1, L0, L1, SQ)                                   \
  do {                                                                     \
    _Pragma("unroll")                                                      \
    for (int t = 0; t < 4; ++t) {                                          \
      float4v a;                                                           \
      a[0] = -0.5f * SQ.x;                                                 \
      a[1] = -0.5f * SQ.y;                                                 \
      a[2] = -0.5f * SQ.z;                                                 \
      a[3] = -0.5f * SQ.w;                                                 \
      a = MFMA16(H0, qh[t][0], a);                                         \
      a = MFMA16(H1, qh[t][1], a);                                         \
      a = MFMA16(L0, qh[t][0], a);                                         \
      a = MFMA16(L1, qh[t][1], a);                                         \
      a = MFMA16(H0, qlo[t][0], a);                                        \
      a = MFMA16(H1, qlo[t][1], a);                                        \
      bmr[t] = fmaxf(bmr[t], fmaxf(fmaxf(a[0], a[1]), fmaxf(a[2], a[3]))); \
    }                                                                      \
  } while (0)

template <int BST>  // steps per bmin block (8 or 16)
__global__ __launch_bounds__(256, 3) void k_phaseA(
    const ushort* __restrict__ Sh, const ushort* __restrict__ Sl,
    const ushort* __restrict__ Qh, const ushort* __restrict__ Ql,
    const float* __restrict__ sqS, float* __restrict__ bmin) {
  constexpr int NSB = NTOT / (16 * BST);   // bmin blocks total (128 or 64)
  const int tid = threadIdx.x;
  const int l = tid & 63;
  const int w = tid >> 6;
  const int lm = l & 15;
  const int lq = l >> 4;
  const int split = blockIdx.x;       // 0..7
  const int qbase = blockIdx.y * 64;
  const int sbase = split * 2048 + w * 512;

  // Query (B) fragments, hi and lo: pinned (resident, R12-proven).
  short8 qh[4][2], qlo[4][2];
#pragma unroll
  for (int t = 0; t < 4; ++t) {
    const size_t pb = (size_t)((qbase >> 4) + t) * 1024 + (size_t)l * 8;
    qh[t][0] = *(const short8*)&Qh[pb];
    qh[t][1] = *(const short8*)&Qh[pb + 512];
    qlo[t][0] = *(const short8*)&Ql[pb];
    qlo[t][1] = *(const short8*)&Ql[pb + 512];
  }
#pragma unroll
  for (int t = 0; t < 4; ++t) {
    pin8(qh[t][0]);
    pin8(qh[t][1]);
    pin8(qlo[t][0]);
    pin8(qlo[t][1]);
  }

  const ushort* pSh = Sh + (size_t)(sbase >> 4) * 1024 + (size_t)l * 8;
  const ushort* pSl = Sl + (size_t)(sbase >> 4) * 1024 + (size_t)l * 8;
  const float* psq = sqS + sbase + lq * 4;

  // Copy-free double buffer: even steps use (a), odd steps use (b).
  short8 h0a = *(const short8*)(pSh);
  short8 h1a = *(const short8*)(pSh + 512);
  short8 l0a = *(const short8*)(pSl);
  short8 l1a = *(const short8*)(pSl + 512);
  float4 sqa = *(const float4*)(psq);
  short8 h0b = *(const short8*)(pSh + 1024);
  short8 h1b = *(const short8*)(pSh + 1024 + 512);
  short8 l0b = *(const short8*)(pSl + 1024);
  short8 l1b = *(const short8*)(pSl + 1024 + 512);
  float4 sqb = *(const float4*)(psq + 16);

  float bmr[4] = {-FLT_BIG, -FLT_BIG, -FLT_BIG, -FLT_BIG};

  for (int st = 0; st < 32; st += 2) {
    STEP_COMPUTE(h0a, h1a, l0a, l1a, sqa);
    if (st + 2 < 32) {
      const int off = (st + 2) * 1024;
      h0a = *(const short8*)(pSh + off);
      h1a = *(const short8*)(pSh + off + 512);
      l0a = *(const short8*)(pSl + off);
      l1a = *(const short8*)(pSl + off + 512);
      sqa = *(const float4*)(psq + (st + 2) * 16);
    }
    STEP_COMPUTE(h0b, h1b, l0b, l1b, sqb);
    if (st + 3 < 32) {
      const int off = (st + 3) * 1024;
      h0b = *(const short8*)(pSh + off);
      h1b = *(const short8*)(pSh + off + 512);
      l0b = *(const short8*)(pSl + off);
      l1b = *(const short8*)(pSl + off + 512);
      sqb = *(const float4*)(psq + (st + 3) * 16);
    }
    if (((st + 1) & (BST - 1)) == (BST - 1)) {  // finished a bmin block
      const int gb = split * (128 / BST) + w * (32 / BST) + ((st + 1) / BST);
#pragma unroll
      for (int t = 0; t < 4; ++t) {
        float v = bmr[t];
        v = fmaxf(v, __shfl_xor(v, 16, 64));
        v = fmaxf(v, __shfl_xor(v, 32, 64));
        if (lq == 0) bmin[(size_t)(qbase + t * 16 + lm) * NSB + gb] = -2.0f * v;
        bmr[t] = -FLT_BIG;
      }
    }
  }
}

// ---------------------------------------------------------------------------
// Phase B: one wave per query; coalesced rescore from S_T.
template <int SBLK>
__global__ __launch_bounds__(256) void k_phaseB(
    const float* __restrict__ S_T,   // [64][NTOT]
    const float* __restrict__ Q,     // [NTOT][64]
    const float* __restrict__ sqS, const float* __restrict__ bmin,
    const float* __restrict__ onehot, float* __restrict__ out) {
  constexpr int NSB = NTOT / SBLK;    // 64 or 128
  constexpr int NB64 = NSB / 64;      // 1 or 2
  constexpr int SPL = SBLK / 64;      // supports per lane: 4 or 2

  __shared__ float sQrow[4][64];
  const int lane = threadIdx.x & 63;
  const int w = threadIdx.x >> 6;
  const int q = blockIdx.x * 4 + w;

  if (lane < 16)
    *(float4*)&sQrow[w][lane * 4] = *(const float4*)&Q[(size_t)q * DIM + lane * 4];
  __syncthreads();

  float bv[NB64];
#pragma unroll
  for (int j = 0; j < NB64; ++j) bv[j] = bmin[(size_t)q * NSB + j * 64 + lane];
  float m = bv[0];
#pragma unroll
  for (int j = 1; j < NB64; ++j) m = fminf(m, bv[j]);
#pragma unroll
  for (int d = 1; d < 64; d <<= 1) m = fminf(m, __shfl_xor(m, d, 64));
  const float thr = m + EPS;

  float bk = FLT_BIG;
  int bi = 0;
#pragma unroll
  for (int j = 0; j < NB64; ++j) {
    unsigned long long msk = __ballot(bv[j] <= thr);
    while (msk) {  // ascending block order; wave-uniform control
      const int b = j * 64 + (__ffsll((long long)msk) - 1);
      msk &= msk - 1;
      const int s0 = b * SBLK + lane * SPL;
      if (SPL == 4) {
        float a0 = 0.f, a1 = 0.f, a2 = 0.f, a3 = 0.f;
#pragma unroll
        for (int c = 0; c < 16; ++c) {
          const float4 qv = *(const float4*)&sQrow[w][c * 4];
          const float4 s0v = *(const float4*)&S_T[(size_t)(c * 4 + 0) * NTOT + s0];
          const float4 s1v = *(const float4*)&S_T[(size_t)(c * 4 + 1) * NTOT + s0];
          const float4 s2v = *(const float4*)&S_T[(size_t)(c * 4 + 2) * NTOT + s0];
          const float4 s3v = *(const float4*)&S_T[(size_t)(c * 4 + 3) * NTOT + s0];
          a0 = fmaf(qv.x, s0v.x, a0); a1 = fmaf(qv.x, s0v.y, a1);
          a2 = fmaf(qv.x, s0v.z, a2); a3 = fmaf(qv.x, s0v.w, a3);
          a0 = fmaf(qv.y, s1v.x, a0); a1 = fmaf(qv.y, s1v.y, a1);
          a2 = fmaf(qv.y, s1v.z, a2); a3 = fmaf(qv.y, s1v.w, a3);
          a0 = fmaf(qv.z, s2v.x, a0); a1 = fmaf(qv.z, s2v.y, a1);
          a2 = fmaf(qv.z, s2v.z, a2); a3 = fmaf(qv.z, s2v.w, a3);
          a0 = fmaf(qv.w, s3v.x, a0); a1 = fmaf(qv.w, s3v.y, a1);
          a2 = fmaf(qv.w, s3v.z, a2); a3 = fmaf(qv.w, s3v.w, a3);
        }
        const float4 sq4 = *(const float4*)&sqS[s0];
        const float k0 = fmaf(-2.f, a0, sq4.x);
        const float k1 = fmaf(-2.f, a1, sq4.y);
        const float k2 = fmaf(-2.f, a2, sq4.z);
        const float k3 = fmaf(-2.f, a3, sq4.w);
        bool u;  // ascending index, strict <
        u = k0 < bk; bk = u ? k0 : bk; bi = u ? s0 : bi;
        u = k1 < bk; bk = u ? k1 : bk; bi = u ? (s0 + 1) : bi;
        u = k2 < bk; bk = u ? k2 : bk; bi = u ? (s0 + 2) : bi;
        u = k3 < bk; bk = u ? k3 : bk; bi = u ? (s0 + 3) : bi;
      } else {
        float a0 = 0.f, a1 = 0.f;
#pragma unroll
        for (int c = 0; c < 16; ++c) {
          const float4 qv = *(const float4*)&sQrow[w][c * 4];
          const float2 s0v = *(const float2*)&S_T[(size_t)(c * 4 + 0) * NTOT + s0];
          const float2 s1v = *(const float2*)&S_T[(size_t)(c * 4 + 1) * NTOT + s0];
          const float2 s2v = *(const float2*)&S_T[(size_t)(c * 4 + 2) * NTOT + s0];
          const float2 s3v = *(const float2*)&S_T[(size_t)(c * 4 + 3) * NTOT + s0];
          a0 = fmaf(qv.x, s0v.x, a0); a1 = fmaf(qv.x, s0v.y, a1);
          a0 = fmaf(qv.y, s1v.x, a0); a1 = fmaf(qv.y, s1v.y, a1);
          a0 = fmaf(qv.z, s2v.x, a0); a1 = fmaf(qv.z, s2v.y, a1);
          a0 = fmaf(qv.w, s3v.x, a0); a1 = fmaf(qv.w, s3v.y, a1);
        }
        const float2 sq2 = *(const float2*)&sqS[s0];
        const float k0 = fmaf(-2.f, a0, sq2.x);
        const float k1 = fmaf(-2.f, a1, sq2.y);
        bool u;
        u = k0 < bk; bk = u ? k0 : bk; bi = u ? s0 : bi;
        u = k1 < bk; bk = u ? k1 : bk; bi = u ? (s0 + 1) : bi;
      }
    }
  }
  // Cross-lane lexicographic argmin on exact keys => first-index semantics.
#pragma unroll
  for (int d = 1; d < 64; d <<= 1) {
    const float ok = __shfl_xor(bk, d, 64);
    const int oi = __shfl_xor(bi, d, 64);
    const bool u = (ok < bk) || (ok == bk && oi < bi);
    bk = u ? ok : bk;
    bi = u ? oi : bi;
  }
  // Label: one-hot rows exact {0,1}; first 1 == np.argmax.
  const float ov = onehot[(size_t)bi * 64 + lane];
  const unsigned long long lmask = __ballot(ov > 0.5f);
  const int label = __ffsll((long long)lmask) - 1;
  out[(size_t)q * 64 + lane] = (lane == label) ? 1.0f : 0.0f;
}

// ---------------------------------------------------------------------------
extern "C" void kernel_launch(void* const* d_in, const int* in_sizes, int n_in,
                              void* d_out, int out_size, void* d_ws, size_t ws_size,
                              hipStream_t stream) {
  const float* S = (const float*)d_in[0];   // [16384][64]
  const float* Q = (const float*)d_in[1];   // [16384][64]
  const float* OH = (const float*)d_in[2];  // [16384][64]
  float* out = (float*)d_out;

  char* ws = (char*)d_ws;
  ushort* Sh = (ushort*)ws;                                  // [0, 2MB)
  ushort* Sl = (ushort*)(ws + (2u << 20));                   // [2, 4MB)
  ushort* Qh = (ushort*)(ws + (4u << 20));                   // [4, 6MB)
  ushort* Ql = (ushort*)(ws + (6u << 20));                   // [6, 8MB)

  // Path A (ws >= 20.07 MB, proven available in R14): 128-granular bmin,
  // dedicated S_T, fused prep, 3 launches.
  // Path B (12.07 MB, R12-proven): 256-granular, S_T aliases, 4 launches.
  const bool pathA = ws_size >= ((20u << 20) + (64u << 10));
  if (pathA) {
    float* S_T = (float*)(ws + (8u << 20));                  // [8, 12MB)
    float* sqS = (float*)(ws + (12u << 20));                 // 64 KB
    float* bmin = (float*)(ws + (12u << 20) + (64u << 10));  // 8 MB
    k_prep<<<dim3(512), 256, 0, stream>>>(S, Q, Sh, Sl, Qh, Ql, sqS, S_T);
    k_phaseA<8><<<dim3(8, NTOT / 64), 256, 0, stream>>>(Sh, Sl, Qh, Ql, sqS, bmin);
    k_phaseB<128><<<dim3(NTOT / 4), 256, 0, stream>>>(S_T, Q, sqS, bmin, OH, out);
  } else {
    float* S_T = (float*)ws;                                 // aliases Sh+Sl
    float* sqS = (float*)(ws + (8u << 20));                  // 64 KB
    float* bmin = (float*)(ws + (8u << 20) + (64u << 10));   // 4 MB
    k_prep<<<dim3(512), 256, 0, stream>>>(S, Q, Sh, Sl, Qh, Ql, sqS, nullptr);
    k_phaseA<16><<<dim3(8, NTOT / 64), 256, 0, stream>>>(Sh, Sl, Qh, Ql, sqS, bmin);
    k_transpose<<<dim3(NTOT / 64), 256, 0, stream>>>(S, S_T);
    k_phaseB<256><<<dim3(NTOT / 4), 256, 0, stream>>>(S_T, Q, sqS, bmin, OH, out);
  }
  (void)in_sizes; (void)n_in; (void)out_size; (void)ws_size;
}

// Round 16
// 161.660 us; speedup vs baseline: 1.9609x; 1.1513x over previous
//
#include <hip/hip_runtime.h>

// KNN argmin over L2, round 16: fp16 SINGLE-TERM MFMA filter.
//
// bf16 (8-bit mantissa) forced a 3-term split to keep EPS small. fp16 has
// 11-bit precision: cross_a = f16(s) . f16(q) in ONE term has certified
// error |Δkey| <= 2^-9 * 1.01 * |s||q|  (RNE rel err 2^-11 per factor,
// fp32 MFMA accumulation exact to ~1e-5). Per-query threshold:
//   EPS_q = 0.005 * sqrt(maxS2 * |q|^2) + 0.05   (>= 2*Δkey_max, w/ slack
//   covering f16-subnormal flush, lo-rounding and accumulation terms).
// maxS2 = max_s |s|^2 computed in prep via device atomicMax (positive
// floats are int-monotone). Rescoring every 128-block with
// bmin <= min + EPS_q provably contains the true first argmin.
//
// phaseA: 8 MFMA/step (was 24) -> issue floor 15.5us; VALU trimmed by
// hoisting the shared -0.5*sq C-init out of the tile loop. No Sl/Ql arrays
// -> prep halves, no aliasing, no transpose kernel, 3 launches + 1 memset.
// phaseB: R15 S_T rescore + per-query EPS. Exact fp32, strict-< ascending,
// lexicographic cross-lane => np.argmin first-index semantics.

#define NTOT   16384
#define DIM    64
#define EPS_COEF 0.005f
#define EPS_ABS  0.05f
#define FLT_BIG 3.4e38f

typedef __attribute__((ext_vector_type(8))) short short8;
typedef __attribute__((ext_vector_type(4))) float float4v;

__device__ __forceinline__ ushort f16_bits(float x) {
  union { _Float16 f; ushort u; } c;
  c.f = (_Float16)x;  // v_cvt_f16_f32, RNE
  return c.u;
}

// Opaque def: forbids rematerialization (forces register residency).
__device__ __forceinline__ void pin8(short8& v) {
  asm volatile("" : "+v"(v));
}

// ---------------------------------------------------------------------------
// Fused prep: blocks 0..255 -> S (f16 panels + sqS + S_T + maxS2);
// blocks 256..511 -> Q (f16 panels + sqQ). Panel layout (R8-proven):
//   off(r,k) = (r>>4)*1024 + (k>>5)*512 + (((k&31)>>3)*16 + (r&15))*8 + (k&7)
__global__ __launch_bounds__(256) void k_prep(
    const float* __restrict__ S, const float* __restrict__ Q,
    ushort* __restrict__ Sh, ushort* __restrict__ Qh,
    float* __restrict__ sqS, float* __restrict__ sqQ,
    float* __restrict__ S_T, int* __restrict__ maxS2) {
  __shared__ float tile[64][65];
  const int tid = threadIdx.x;
  const bool isS = blockIdx.x < 256;
  const int rbase = (blockIdx.x & 255) * 64;
  const float* __restrict__ src = isS ? S : Q;
  ushort* __restrict__ dh = isS ? Sh : Qh;

  const int tx = tid & 63;
  const int ty = tid >> 6;
#pragma unroll
  for (int i = 0; i < 16; ++i) {
    const int r = i * 4 + ty;
    tile[r][tx] = src[(size_t)(rbase + r) * DIM + tx];  // coalesced
  }
  __syncthreads();

  if (isS) {  // transposed copy (coalesced, pad-safe)
#pragma unroll
    for (int i = 0; i < 16; ++i) {
      const int d = i * 4 + ty;
      S_T[(size_t)d * NTOT + rbase + tx] = tile[tx][d];
    }
  }

  // Panel-swizzled f16; stores are lane-contiguous 16B.
  const int panel = tid >> 6;           // 0..3
  const int half = (tid >> 5) & 1;      // k-half
  const int slot0 = (tid & 31) * 2;     // slot = q8*16 + m
#pragma unroll
  for (int ss = 0; ss < 2; ++ss) {
    const int s = slot0 + ss;
    const int m = s & 15;
    const int q8 = s >> 4;
    const int row = panel * 16 + m;
    const int kb = half * 32 + q8 * 8;
    short8 hv;
#pragma unroll
    for (int j = 0; j < 8; ++j) hv[j] = (short)f16_bits(tile[row][kb + j]);
    const size_t goff =
        (size_t)((rbase >> 4) + panel) * 1024 + (size_t)half * 512 + (size_t)s * 8;
    *(short8*)&dh[goff] = hv;
  }

  // Row sum of squares (+ S-side global max via atomicMax on int bits).
  if (tid < 64) {
    float acc = 0.0f;
#pragma unroll
    for (int d = 0; d < DIM; ++d) {
      const float v = tile[tid][d];
      acc = fmaf(v, v, acc);
    }
    (isS ? sqS : sqQ)[rbase + tid] = acc;
    if (isS) {
      float mx = acc;
#pragma unroll
      for (int d = 1; d < 64; d <<= 1) mx = fmaxf(mx, __shfl_xor(mx, d, 64));
      if (tid == 0) atomicMax(maxS2, __float_as_int(mx));  // positive floats
    }
  }
}

// ---------------------------------------------------------------------------
// Phase A: block = 4 waves; wave w: 64 queries x 512 supports.
// grid = (8 splits, 256 q-tiles). 16x16x32 f16 MFMA (same fragment layout
// as the R4-R15 HW-verified bf16 family). 2 MFMA per tile chain; C init
// -0.5*sq shared across the 4 tiles (hoisted, 4 VALU/step).

#define MFMA16F(A, B, C) __builtin_amdgcn_mfma_f32_16x16x32_f16(A, B, C, 0, 0, 0)

#define STEP_COMPUTE(H0, H1, SQ)                                           \
  do {                                                                     \
    float4v cinit;                                                         \
    cinit[0] = -0.5f * SQ.x;                                               \
    cinit[1] = -0.5f * SQ.y;                                               \
    cinit[2] = -0.5f * SQ.z;                                               \
    cinit[3] = -0.5f * SQ.w;                                               \
    _Pragma("unroll")                                                      \
    for (int t = 0; t < 4; ++t) {                                          \
      float4v a = MFMA16F(H0, qh[t][0], cinit);                            \
      a = MFMA16F(H1, qh[t][1], a);                                        \
      bmr[t] = fmaxf(bmr[t], fmaxf(fmaxf(a[0], a[1]), fmaxf(a[2], a[3]))); \
    }                                                                      \
  } while (0)

template <int BST>  // steps per bmin block (8 -> 128-support granularity)
__global__ __launch_bounds__(256, 3) void k_phaseA(
    const ushort* __restrict__ Sh, const ushort* __restrict__ Qh,
    const float* __restrict__ sqS, float* __restrict__ bmin) {
  constexpr int NSB = NTOT / (16 * BST);
  const int tid = threadIdx.x;
  const int l = tid & 63;
  const int w = tid >> 6;
  const int lm = l & 15;
  const int lq = l >> 4;
  const int split = blockIdx.x;       // 0..7
  const int qbase = blockIdx.y * 64;
  const int sbase = split * 2048 + w * 512;

  // Query (B) fragments: 4 tiles x 2 k-chunks, pinned (resident).
  short8 qh[4][2];
#pragma unroll
  for (int t = 0; t < 4; ++t) {
    const size_t pb = (size_t)((qbase >> 4) + t) * 1024 + (size_t)l * 8;
    qh[t][0] = *(const short8*)&Qh[pb];
    qh[t][1] = *(const short8*)&Qh[pb + 512];
  }
#pragma unroll
  for (int t = 0; t < 4; ++t) {
    pin8(qh[t][0]);
    pin8(qh[t][1]);
  }

  const ushort* pSh = Sh + (size_t)(sbase >> 4) * 1024 + (size_t)l * 8;
  const float* psq = sqS + sbase + lq * 4;

  // Copy-free double buffer: even steps use (a), odd steps use (b).
  short8 h0a = *(const short8*)(pSh);
  short8 h1a = *(const short8*)(pSh + 512);
  float4 sqa = *(const float4*)(psq);
  short8 h0b = *(const short8*)(pSh + 1024);
  short8 h1b = *(const short8*)(pSh + 1024 + 512);
  float4 sqb = *(const float4*)(psq + 16);

  float bmr[4] = {-FLT_BIG, -FLT_BIG, -FLT_BIG, -FLT_BIG};

  for (int st = 0; st < 32; st += 2) {
    STEP_COMPUTE(h0a, h1a, sqa);
    if (st + 2 < 32) {
      const int off = (st + 2) * 1024;
      h0a = *(const short8*)(pSh + off);
      h1a = *(const short8*)(pSh + off + 512);
      sqa = *(const float4*)(psq + (st + 2) * 16);
    }
    STEP_COMPUTE(h0b, h1b, sqb);
    if (st + 3 < 32) {
      const int off = (st + 3) * 1024;
      h0b = *(const short8*)(pSh + off);
      h1b = *(const short8*)(pSh + off + 512);
      sqb = *(const float4*)(psq + (st + 3) * 16);
    }
    if (((st + 1) & (BST - 1)) == (BST - 1)) {  // finished a bmin block
      const int gb = split * (128 / BST) + w * (32 / BST) + ((st + 1) / BST);
#pragma unroll
      for (int t = 0; t < 4; ++t) {
        float v = bmr[t];
        v = fmaxf(v, __shfl_xor(v, 16, 64));
        v = fmaxf(v, __shfl_xor(v, 32, 64));
        if (lq == 0) bmin[(size_t)(qbase + t * 16 + lm) * NSB + gb] = -2.0f * v;
        bmr[t] = -FLT_BIG;
      }
    }
  }
}

// ---------------------------------------------------------------------------
// Phase B: one wave per query; coalesced rescore from S_T; per-query EPS.
template <int SBLK>
__global__ __launch_bounds__(256) void k_phaseB(
    const float* __restrict__ S_T,   // [64][NTOT]
    const float* __restrict__ Q,     // [NTOT][64]
    const float* __restrict__ sqS, const float* __restrict__ sqQ,
    const int* __restrict__ maxS2, const float* __restrict__ bmin,
    const float* __restrict__ onehot, float* __restrict__ out) {
  constexpr int NSB = NTOT / SBLK;    // 128 or 64
  constexpr int NB64 = NSB / 64;
  constexpr int SPL = SBLK / 64;      // supports per lane: 2 or 4

  __shared__ float sQrow[4][64];
  const int lane = threadIdx.x & 63;
  const int w = threadIdx.x >> 6;
  const int q = blockIdx.x * 4 + w;

  if (lane < 16)
    *(float4*)&sQrow[w][lane * 4] = *(const float4*)&Q[(size_t)q * DIM + lane * 4];
  __syncthreads();

  // Per-query certified filter width.
  const float ms2 = __int_as_float(*maxS2);
  const float eps = EPS_COEF * sqrtf(ms2 * sqQ[q]) + EPS_ABS;

  float bv[NB64];
#pragma unroll
  for (int j = 0; j < NB64; ++j) bv[j] = bmin[(size_t)q * NSB + j * 64 + lane];
  float m = bv[0];
#pragma unroll
  for (int j = 1; j < NB64; ++j) m = fminf(m, bv[j]);
#pragma unroll
  for (int d = 1; d < 64; d <<= 1) m = fminf(m, __shfl_xor(m, d, 64));
  const float thr = m + eps;

  float bk = FLT_BIG;
  int bi = 0;
#pragma unroll
  for (int j = 0; j < NB64; ++j) {
    unsigned long long msk = __ballot(bv[j] <= thr);
    while (msk) {  // ascending block order; wave-uniform control
      const int b = j * 64 + (__ffsll((long long)msk) - 1);
      msk &= msk - 1;
      const int s0 = b * SBLK + lane * SPL;
      if (SPL == 4) {
        float a0 = 0.f, a1 = 0.f, a2 = 0.f, a3 = 0.f;
#pragma unroll
        for (int c = 0; c < 16; ++c) {
          const float4 qv = *(const float4*)&sQrow[w][c * 4];
          const float4 s0v = *(const float4*)&S_T[(size_t)(c * 4 + 0) * NTOT + s0];
          const float4 s1v = *(const float4*)&S_T[(size_t)(c * 4 + 1) * NTOT + s0];
          const float4 s2v = *(const float4*)&S_T[(size_t)(c * 4 + 2) * NTOT + s0];
          const float4 s3v = *(const float4*)&S_T[(size_t)(c * 4 + 3) * NTOT + s0];
          a0 = fmaf(qv.x, s0v.x, a0); a1 = fmaf(qv.x, s0v.y, a1);
          a2 = fmaf(qv.x, s0v.z, a2); a3 = fmaf(qv.x, s0v.w, a3);
          a0 = fmaf(qv.y, s1v.x, a0); a1 = fmaf(qv.y, s1v.y, a1);
          a2 = fmaf(qv.y, s1v.z, a2); a3 = fmaf(qv.y, s1v.w, a3);
          a0 = fmaf(qv.z, s2v.x, a0); a1 = fmaf(qv.z, s2v.y, a1);
          a2 = fmaf(qv.z, s2v.z, a2); a3 = fmaf(qv.z, s2v.w, a3);
          a0 = fmaf(qv.w, s3v.x, a0); a1 = fmaf(qv.w, s3v.y, a1);
          a2 = fmaf(qv.w, s3v.z, a2); a3 = fmaf(qv.w, s3v.w, a3);
        }
        const float4 sq4 = *(const float4*)&sqS[s0];
        const float k0 = fmaf(-2.f, a0, sq4.x);
        const float k1 = fmaf(-2.f, a1, sq4.y);
        const float k2 = fmaf(-2.f, a2, sq4.z);
        const float k3 = fmaf(-2.f, a3, sq4.w);
        bool u;  // ascending index, strict <
        u = k0 < bk; bk = u ? k0 : bk; bi = u ? s0 : bi;
        u = k1 < bk; bk = u ? k1 : bk; bi = u ? (s0 + 1) : bi;
        u = k2 < bk; bk = u ? k2 : bk; bi = u ? (s0 + 2) : bi;
        u = k3 < bk; bk = u ? k3 : bk; bi = u ? (s0 + 3) : bi;
      } else {
        float a0 = 0.f, a1 = 0.f;
#pragma unroll
        for (int c = 0; c < 16; ++c) {
          const float4 qv = *(const float4*)&sQrow[w][c * 4];
          const float2 s0v = *(const float2*)&S_T[(size_t)(c * 4 + 0) * NTOT + s0];
          const float2 s1v = *(const float2*)&S_T[(size_t)(c * 4 + 1) * NTOT + s0];
          const float2 s2v = *(const float2*)&S_T[(size_t)(c * 4 + 2) * NTOT + s0];
          const float2 s3v = *(const float2*)&S_T[(size_t)(c * 4 + 3) * NTOT + s0];
          a0 = fmaf(qv.x, s0v.x, a0); a1 = fmaf(qv.x, s0v.y, a1);
          a0 = fmaf(qv.y, s1v.x, a0); a1 = fmaf(qv.y, s1v.y, a1);
          a0 = fmaf(qv.z, s2v.x, a0); a1 = fmaf(qv.z, s2v.y, a1);
          a0 = fmaf(qv.w, s3v.x, a0); a1 = fmaf(qv.w, s3v.y, a1);
        }
        const float2 sq2 = *(const float2*)&sqS[s0];
        const float k0 = fmaf(-2.f, a0, sq2.x);
        const float k1 = fmaf(-2.f, a1, sq2.y);
        bool u;
        u = k0 < bk; bk = u ? k0 : bk; bi = u ? s0 : bi;
        u = k1 < bk; bk = u ? k1 : bk; bi = u ? (s0 + 1) : bi;
      }
    }
  }
  // Cross-lane lexicographic argmin on exact keys => first-index semantics.
#pragma unroll
  for (int d = 1; d < 64; d <<= 1) {
    const float ok = __shfl_xor(bk, d, 64);
    const int oi = __shfl_xor(bi, d, 64);
    const bool u = (ok < bk) || (ok == bk && oi < bi);
    bk = u ? ok : bk;
    bi = u ? oi : bi;
  }
  // Label: one-hot rows exact {0,1}; first 1 == np.argmax.
  const float ov = onehot[(size_t)bi * 64 + lane];
  const unsigned long long lmask = __ballot(ov > 0.5f);
  const int label = __ffsll((long long)lmask) - 1;
  out[(size_t)q * 64 + lane] = (lane == label) ? 1.0f : 0.0f;
}

// ---------------------------------------------------------------------------
extern "C" void kernel_launch(void* const* d_in, const int* in_sizes, int n_in,
                              void* d_out, int out_size, void* d_ws, size_t ws_size,
                              hipStream_t stream) {
  const float* S = (const float*)d_in[0];   // [16384][64]
  const float* Q = (const float*)d_in[1];   // [16384][64]
  const float* OH = (const float*)d_in[2];  // [16384][64]
  float* out = (float*)d_out;

  char* ws = (char*)d_ws;
  ushort* Sh = (ushort*)ws;                                  // [0, 2MB)
  ushort* Qh = (ushort*)(ws + (2u << 20));                   // [2, 4MB)
  float* S_T = (float*)(ws + (4u << 20));                    // [4, 8MB)
  float* sqS = (float*)(ws + (8u << 20));                    // 64 KB
  float* sqQ = (float*)(ws + (8u << 20) + (64u << 10));      // 64 KB
  int* mS2 = (int*)(ws + (8u << 20) + (128u << 10));         // 64 KB slot
  float* bmin = (float*)(ws + (8u << 20) + (192u << 10));    // up to 8 MB

  hipMemsetAsync(mS2, 0, 4, stream);  // maxS2 accumulator (stream op: ok)
  k_prep<<<dim3(512), 256, 0, stream>>>(S, Q, Sh, Qh, sqS, sqQ, S_T, mS2);

  // 128-granular bmin (8 MB) if workspace allows (proven >=20 MB in R14);
  // else 256-granular (4 MB). Total need: 8.19 + 8 = 16.19 MB / 12.19 MB.
  if (ws_size >= (17u << 20)) {
    k_phaseA<8><<<dim3(8, NTOT / 64), 256, 0, stream>>>(Sh, Qh, sqS, bmin);
    k_phaseB<128><<<dim3(NTOT / 4), 256, 0, stream>>>(S_T, Q, sqS, sqQ, mS2,
                                                      bmin, OH, out);
  } else {
    k_phaseA<16><<<dim3(8, NTOT / 64), 256, 0, stream>>>(Sh, Qh, sqS, bmin);
    k_phaseB<256><<<dim3(NTOT / 4), 256, 0, stream>>>(S_T, Q, sqS, sqQ, mS2,
                                                      bmin, OH, out);
  }
  (void)in_sizes; (void)n_in; (void)out_size; (void)ws_size;
}